// Round 6
// baseline (347.025 us; speedup 1.0000x reference)
//
#include <hip/hip_runtime.h>

#define CC 192
#define WFRAG_USHORTS (4*6*12*512)
#define SX 202   // [tok][ch] stride (ushorts): 404B = 101 dwords == 5 mod 32
#define SV 74    // [ch][tok] stride (ushorts): 148B = 37 dwords == 5 mod 32

typedef __attribute__((ext_vector_type(8))) short bf16x8;
typedef __attribute__((ext_vector_type(4))) float f32x4;

__device__ __forceinline__ unsigned short f2b(float f){
  unsigned u = __float_as_uint(f);
  return (unsigned short)((u + 0x7fffu + ((u >> 16) & 1u)) >> 16);
}
__device__ __forceinline__ unsigned pk2(float a, float b){
  return (unsigned)f2b(a) | ((unsigned)f2b(b) << 16);
}

// Weights packed in MFMA-fragment order: Wf[mat][k][n][lane][8]; one wave
// B/A-fragment = one contiguous 1KB block. 1/sqrt(32) folded into Q mat+bias.
__global__ void fuse_weights(const float* __restrict__ wq, const float* __restrict__ bq,
                             const float* __restrict__ wk, const float* __restrict__ bk,
                             const float* __restrict__ wv, const float* __restrict__ bv,
                             const float* __restrict__ in_w, const float* __restrict__ in_b,
                             const float* __restrict__ out_w, const float* __restrict__ out_b,
                             const float* __restrict__ proj_w, const float* __restrict__ proj_b,
                             unsigned short* __restrict__ Wf, float* __restrict__ Bf)
{
  int mat = blockIdx.x / CC, o = blockIdx.x % CC, ci = threadIdx.x;
  const float *A, *Bm, *bs, *ba; int aoff, boff; float scale = 1.f;
  if (mat == 0){ A=in_w; aoff=0;    Bm=wq;    bs=bq;    ba=in_b;   boff=0;    scale=0.17677669529663687f; }
  else if (mat==1){ A=in_w; aoff=CC;   Bm=wk;    bs=bk;    ba=in_b;   boff=CC;   }
  else if (mat==2){ A=in_w; aoff=2*CC; Bm=wv;    bs=bv;    ba=in_b;   boff=2*CC; }
  else            { A=proj_w; aoff=0;  Bm=out_w; bs=out_b; ba=proj_b; boff=0;    }
  const float* ar = A + (size_t)(aoff + o) * CC;
  float acc = 0.f;
  for (int m = 0; m < CC; ++m) acc = fmaf(ar[m], Bm[m*CC + ci], acc);
  int k = ci >> 5, n = o >> 4, lgv = (ci >> 3) & 3, e = ci & 7;
  int lane = (o & 15) | (lgv << 4);
  Wf[(((mat*6 + k)*12 + n) << 9) + lane*8 + e] = f2b(acc * scale);
  if (ci == 0){
    float bacc = 0.f;
    for (int m = 0; m < CC; ++m) bacc = fmaf(ar[m], bs[m], bacc);
    Bf[mat*CC + o] = (bacc + ba[boff + o]) * scale;
  }
}

__global__ __launch_bounds__(512, 4) void win_attn(
    const float* __restrict__ q2d, const float* __restrict__ kv2d,
    const unsigned short* __restrict__ Wf, const float* __restrict__ Bf,
    float* __restrict__ out)
{
  __shared__ unsigned short QK[2][64*SX]; // [0]: Xq -> Q -> O ; [1]: Xkv -> K
  __shared__ unsigned short VT[192*SV];   // V^T [ch][tok]

  const int t = threadIdx.x;
  const int w = t >> 6, lane = t & 63, lr = lane & 15, lg = lane >> 4;
  const int bid = blockIdx.x;
  const int wid = (bid & 7) * 512 + (bid >> 3);   // XCD-chunked, bijective
  const int b = wid >> 10, l = wid & 1023;
  const int y0 = (l >> 5) << 3, x0 = (l & 31) << 3;
  const float* qsrc  = q2d  + (size_t)b * CC * 65536;
  const float* kvsrc = kv2d + (size_t)b * CC * 65536;

  const int mat = w >> 2;        // 0: Q-half duties, 1: K-half duties
  const int tb  = 3 * (w & 3);   // tile base within the half

  auto stage = [&](const float* __restrict__ src, unsigned short* __restrict__ dst){
    #pragma unroll
    for (int i = 0; i < 3; ++i){
      int lin = i*512 + t;
      int c2 = lin >> 4, tok0 = (lin & 15) << 2;
      int gy = (y0 + (tok0 >> 3)) * 256 + x0 + (tok0 & 7);
      float4 va = *(const float4*)&src[(size_t)(2*c2)   * 65536 + gy];
      float4 vb = *(const float4*)&src[(size_t)(2*c2+1) * 65536 + gy];
      float fa[4] = {va.x, va.y, va.z, va.w};
      float fb[4] = {vb.x, vb.y, vb.z, vb.w};
      #pragma unroll
      for (int j = 0; j < 4; ++j)
        *(unsigned*)&dst[(tok0 + j)*SX + 2*c2] = pk2(fa[j], fb[j]);
    }
  };

  stage(qsrc,  QK[0]);
  stage(kvsrc, QK[1]);
  __syncthreads();

  // ---- Phase A: projections. Wave (mat,tb): {Q|K} tiles tb..tb+2 (M=64),
  //      plus V tiles tb..tb+2 on token-half mat (M=32). All in registers. ----
  const unsigned short* Xs = QK[mat];
  f32x4 qk[3][4] = {};
  f32x4 vv[3][2] = {};
  #pragma unroll
  for (int k = 0; k < 6; ++k){
    bf16x8 a[4];
    #pragma unroll
    for (int m = 0; m < 4; ++m)
      a[m] = *(const bf16x8*)&Xs[(m*16 + lr)*SX + k*32 + lg*8];
    bf16x8 av[2];
    #pragma unroll
    for (int mi = 0; mi < 2; ++mi)
      av[mi] = *(const bf16x8*)&QK[1][((2*mat + mi)*16 + lr)*SX + k*32 + lg*8];
    #pragma unroll
    for (int i = 0; i < 3; ++i){
      bf16x8 bw = *(const bf16x8*)&Wf[(((mat*6 + k)*12 + tb + i) << 9) + lane*8];
      #pragma unroll
      for (int m = 0; m < 4; ++m)
        qk[i][m] = __builtin_amdgcn_mfma_f32_16x16x32_bf16(a[m], bw, qk[i][m], 0, 0, 0);
      bf16x8 bv = *(const bf16x8*)&Wf[(((12 + k)*12 + tb + i) << 9) + lane*8];
      #pragma unroll
      for (int mi = 0; mi < 2; ++mi)
        vv[i][mi] = __builtin_amdgcn_mfma_f32_16x16x32_bf16(av[mi], bv, vv[i][mi], 0, 0, 0);
    }
  }
  // V -> VT now (VT not aliased with X buffers)
  #pragma unroll
  for (int i = 0; i < 3; ++i){
    int ch = (tb + i)*16 + lr;
    float bb = Bf[2*CC + ch];
    #pragma unroll
    for (int mi = 0; mi < 2; ++mi){
      int tk = (2*mat + mi)*16 + lg*4;
      *(unsigned*)&VT[ch*SV + tk]     = pk2(vv[i][mi][0] + bb, vv[i][mi][1] + bb);
      *(unsigned*)&VT[ch*SV + tk + 2] = pk2(vv[i][mi][2] + bb, vv[i][mi][3] + bb);
    }
  }
  __syncthreads();          // all X reads complete -> QK[] reusable

  { // write Q -> QK[0] (mat=0 waves), K -> QK[1] (mat=1 waves)
    unsigned short* dst = QK[mat];
    #pragma unroll
    for (int i = 0; i < 3; ++i){
      int ch = (tb + i)*16 + lr;
      float bb = Bf[mat*CC + ch];
      #pragma unroll
      for (int m = 0; m < 4; ++m)
        #pragma unroll
        for (int rr = 0; rr < 4; ++rr)
          dst[(m*16 + lg*4 + rr)*SX + ch] = f2b(qk[i][m][rr] + bb);
    }
  }
  __syncthreads();

  // ---- attention: 24 (head, row-quarter) tasks, 3 per wave; P in regs ----
  #pragma unroll
  for (int i = 0; i < 3; ++i){
    int task = 3*w + i;
    int h = task >> 2, r0 = (task & 3) << 4;
    f32x4 st[4] = {};
    bf16x8 bq_ = *(const bf16x8*)&QK[0][(r0 + lr)*SX + h*32 + lg*8];
    #pragma unroll
    for (int m = 0; m < 4; ++m){
      bf16x8 a = *(const bf16x8*)&QK[1][(m*16 + lr)*SX + h*32 + lg*8];
      st[m] = __builtin_amdgcn_mfma_f32_16x16x32_bf16(a, bq_, st[m], 0, 0, 0);
    }
    float mx = st[0][0];
    #pragma unroll
    for (int m = 0; m < 4; ++m)
      #pragma unroll
      for (int rr = 0; rr < 4; ++rr) mx = fmaxf(mx, st[m][rr]);
    mx = fmaxf(mx, __shfl_xor(mx, 16));
    mx = fmaxf(mx, __shfl_xor(mx, 32));
    float p[16]; float s = 0.f;
    #pragma unroll
    for (int m = 0; m < 4; ++m)
      #pragma unroll
      for (int rr = 0; rr < 4; ++rr){ float e = __expf(st[m][rr] - mx); p[m*4+rr] = e; s += e; }
    s += __shfl_xor(s, 16); s += __shfl_xor(s, 32);
    float inv = 1.f / s;
    #pragma unroll
    for (int i2 = 0; i2 < 16; ++i2) p[i2] *= inv;
    // PV, permuted k-order: A-frag(kt) = own p[8kt..8kt+7]; B from VT
    f32x4 o0 = {}, o1 = {};
    #pragma unroll
    for (int kt = 0; kt < 2; ++kt){
      bf16x8 ap;
      ((unsigned*)&ap)[0] = pk2(p[8*kt+0], p[8*kt+1]);
      ((unsigned*)&ap)[1] = pk2(p[8*kt+2], p[8*kt+3]);
      ((unsigned*)&ap)[2] = pk2(p[8*kt+4], p[8*kt+5]);
      ((unsigned*)&ap)[3] = pk2(p[8*kt+6], p[8*kt+7]);
      bf16x8 v0, v1;
      ((uint2*)&v0)[0] = *(const uint2*)&VT[(h*32 + lr)*SV      + kt*32 + lg*4];
      ((uint2*)&v0)[1] = *(const uint2*)&VT[(h*32 + lr)*SV      + kt*32 + 16 + lg*4];
      ((uint2*)&v1)[0] = *(const uint2*)&VT[(h*32 + 16 + lr)*SV + kt*32 + lg*4];
      ((uint2*)&v1)[1] = *(const uint2*)&VT[(h*32 + 16 + lr)*SV + kt*32 + 16 + lg*4];
      o0 = __builtin_amdgcn_mfma_f32_16x16x32_bf16(ap, v0, o0, 0, 0, 0);
      o1 = __builtin_amdgcn_mfma_f32_16x16x32_bf16(ap, v1, o1, 0, 0, 0);
    }
    // O overwrites this task's own Q cells (sole reader = this wave)
    #pragma unroll
    for (int rr = 0; rr < 4; ++rr){
      int tok = r0 + lg*4 + rr;
      QK[0][tok*SX + h*32 + lr]      = f2b(o0[rr]);
      QK[0][tok*SX + h*32 + 16 + lr] = f2b(o1[rr]);
    }
  }
  __syncthreads();

  // ---- out-proj: E2^T = Wo_f * O^T; wave (mat,tb): tiles tb..tb+2, tok-half mat ----
  {
    f32x4 eo[3][2] = {};
    #pragma unroll
    for (int k = 0; k < 6; ++k){
      bf16x8 bo[2];
      #pragma unroll
      for (int nt = 0; nt < 2; ++nt)
        bo[nt] = *(const bf16x8*)&QK[0][((2*mat + nt)*16 + lr)*SX + k*32 + lg*8];
      #pragma unroll
      for (int i = 0; i < 3; ++i){
        bf16x8 aw = *(const bf16x8*)&Wf[(((18 + k)*12 + tb + i) << 9) + lane*8];
        #pragma unroll
        for (int nt = 0; nt < 2; ++nt)
          eo[i][nt] = __builtin_amdgcn_mfma_f32_16x16x32_bf16(aw, bo[nt], eo[i][nt], 0, 0, 0);
      }
    }
    #pragma unroll
    for (int i = 0; i < 3; ++i){
      #pragma unroll
      for (int rr = 0; rr < 4; ++rr){
        int o = (tb + i)*16 + lg*4 + rr;
        float bb = Bf[3*CC + o];
        #pragma unroll
        for (int nt = 0; nt < 2; ++nt){
          int tok = (2*mat + nt)*16 + lr;
          size_t g = (size_t)(b*CC + o)*65536 + (size_t)(y0 + (tok >> 3))*256 + x0 + (tok & 7);
          out[g] = eo[i][nt][rr] + bb + q2d[g];
        }
      }
    }
  }
}

extern "C" void kernel_launch(void* const* d_in, const int* in_sizes, int n_in,
                              void* d_out, int out_size, void* d_ws, size_t ws_size,
                              hipStream_t stream)
{
  const float* q2d    = (const float*)d_in[0];
  const float* kv2d   = (const float*)d_in[1];
  const float* wq     = (const float*)d_in[2];
  const float* bq     = (const float*)d_in[3];
  const float* wk     = (const float*)d_in[4];
  const float* bk     = (const float*)d_in[5];
  const float* wv     = (const float*)d_in[6];
  const float* bv     = (const float*)d_in[7];
  const float* in_w   = (const float*)d_in[8];
  const float* in_b   = (const float*)d_in[9];
  const float* out_w  = (const float*)d_in[10];
  const float* out_b  = (const float*)d_in[11];
  const float* proj_w = (const float*)d_in[12];
  const float* proj_b = (const float*)d_in[13];

  unsigned short* Wf = (unsigned short*)d_ws;
  float* Bf = (float*)((char*)d_ws + WFRAG_USHORTS*2);
  float* out = (float*)d_out;

  fuse_weights<<<4*CC, CC, 0, stream>>>(wq,bq,wk,bk,wv,bv,in_w,in_b,
                                        out_w,out_b,proj_w,proj_b, Wf, Bf);
  win_attn<<<4096, 512, 0, stream>>>(q2d, kv2d, Wf, Bf, out);
}